// Round 18
// baseline (700.871 us; speedup 1.0000x reference)
//
#include <hip/hip_runtime.h>
#include <math.h>
#include <stdint.h>

#define N_ 512
#define D_ 64
#define K_ 10
#define S_ 10
#define INDIM_ 784
#define H_ 512
#define DP1 (D_ + 1)

typedef __attribute__((ext_vector_type(8))) short short8v;
typedef __attribute__((ext_vector_type(4))) float f32x4;

// ---------------- JAX Threefry-2x32 (20 rounds) ----------------
__device__ __forceinline__ uint32_t rotl32(uint32_t v, int r) { return (v << r) | (v >> (32 - r)); }

__device__ __forceinline__ void threefry2x32(uint32_t k0, uint32_t k1,
                                             uint32_t x0, uint32_t x1,
                                             uint32_t& o0, uint32_t& o1) {
  uint32_t k2 = k0 ^ k1 ^ 0x1BD11BDAu;
  x0 += k0; x1 += k1;
#define TFR(r) { x0 += x1; x1 = rotl32(x1, r); x1 ^= x0; }
  TFR(13) TFR(15) TFR(26) TFR(6)
  x0 += k1; x1 += k2 + 1u;
  TFR(17) TFR(29) TFR(16) TFR(24)
  x0 += k2; x1 += k0 + 2u;
  TFR(13) TFR(15) TFR(26) TFR(6)
  x0 += k0; x1 += k1 + 3u;
  TFR(17) TFR(29) TFR(16) TFR(24)
  x0 += k1; x1 += k2 + 4u;
  TFR(13) TFR(15) TFR(26) TFR(6)
  x0 += k2; x1 += k0 + 5u;
#undef TFR
  o0 = x0; o1 = x1;
}

__device__ __forceinline__ uint32_t jax_bits32(uint32_t k0, uint32_t k1, uint32_t idx) {
  uint32_t o0, o1; threefry2x32(k0, k1, 0u, idx, o0, o1);
  return o0 ^ o1;
}

__device__ __forceinline__ float bits_to_u01(uint32_t bits) {
  return __uint_as_float((bits >> 9) | 0x3F800000u) - 1.0f;
}

__device__ __forceinline__ float erfinv_f32(float x) {
  float w = -log1pf(-x * x);
  float p;
  if (w < 5.0f) {
    w = w - 2.5f;
    p = 2.81022636e-08f;
    p = fmaf(p, w, 3.43273939e-07f);
    p = fmaf(p, w, -3.5233877e-06f);
    p = fmaf(p, w, -4.39150654e-06f);
    p = fmaf(p, w, 0.00021858087f);
    p = fmaf(p, w, -0.00125372503f);
    p = fmaf(p, w, -0.00417768164f);
    p = fmaf(p, w, 0.246640727f);
    p = fmaf(p, w, 1.50140941f);
  } else {
    w = sqrtf(w) - 3.0f;
    p = -0.000200214257f;
    p = fmaf(p, w, 0.000100950558f);
    p = fmaf(p, w, 0.00134934322f);
    p = fmaf(p, w, -0.00367342844f);
    p = fmaf(p, w, 0.00573950773f);
    p = fmaf(p, w, -0.0076224613f);
    p = fmaf(p, w, 0.00943887047f);
    p = fmaf(p, w, 1.00167406f);
    p = fmaf(p, w, 2.83297682f);
  }
  return p * x;
}

__device__ __forceinline__ float jax_normal_f32(uint32_t k0, uint32_t k1, uint32_t idx) {
  uint32_t bits = jax_bits32(k0, k1, idx);
  float u = bits_to_u01(bits);
  const float lo = -0.99999994f;
  float v = u * (1.0f - lo) + lo;
  v = fmaxf(lo, v);
  return 1.41421356f * erfinv_f32(v);
}

__device__ __forceinline__ float jax_gumbel_f32(uint32_t k0, uint32_t k1, uint32_t idx) {
  uint32_t bits = jax_bits32(k0, k1, idx);
  float u = bits_to_u01(bits);
  const float tiny = 1.17549435e-38f;
  float v = u * (1.0f - tiny) + tiny;
  v = fmaxf(tiny, v);
  return -logf(-logf(v));
}

__device__ __forceinline__ float sp32(float x) { return fmaxf(x, 0.f) + log1pf(expf(-fabsf(x))); }
__device__ __forceinline__ float sp32cr(float x) {
  double xd = (double)x;
  return (float)(fmax(xd, 0.0) + log1p(exp(-fabs(xd))));
}
__device__ __forceinline__ double sp64(double x) { return fmax(x, 0.0) + log1p(exp(-fabs(x))); }

__device__ __forceinline__ float fast_sp(float x) {
  float e = __expf(-fabsf(x));
  return fmaxf(x, 0.f) + __logf(1.0f + e);
}
__device__ __forceinline__ float fast_tanh(float x) {
  float xc = fminf(fmaxf(2.0f * x, -30.0f), 30.0f);
  float e = __expf(xc);
  float r = __builtin_amdgcn_rcpf(e + 1.0f);
  return fmaf(-2.0f, r, 1.0f);
}

__device__ __forceinline__ ushort bf16rne(float f) {
  uint32_t u = __float_as_uint(f);
  uint32_t r = (u + 0x7FFFu + ((u >> 16) & 1u)) >> 16;
  return (ushort)r;
}
__device__ __forceinline__ float bf2f(ushort b) { return __uint_as_float(((uint32_t)b) << 16); }

// =============== k_all1: encoder(+muvar) | prep | gmm | lu32 ===============
__global__ __launch_bounds__(256) void k_all1(
    const float* __restrict__ y, const float* __restrict__ eW1, const float* __restrict__ eb1,
    const float* __restrict__ Wmu, const float* __restrict__ bmu,
    const float* __restrict__ Wv, const float* __restrict__ bv,
    double* __restrict__ mu, double* __restrict__ dvec,
    float* __restrict__ d32, float* __restrict__ muph,
    const float* __restrict__ dW1, const float* __restrict__ dWmu, const float* __restrict__ dWv,
    ushort* __restrict__ hF,
    const float* __restrict__ Lraw, const float* __restrict__ piraw, const float* __restrict__ muk,
    double* __restrict__ iJout, double* __restrict__ gko, double* __restrict__ logpi,
    float* __restrict__ J32g, float* __restrict__ LU32g, int* __restrict__ pivg) {
  __shared__ union SM1 {
    struct { double hs[512]; float mu32s[64]; float var32s[64]; } e;
    struct { float Lk[64][DP1]; double dg[64]; double Li[64][DP1]; } g;
    struct { float Lk[64][DP1]; float A[64][DP1]; } u;
  } sm;
  int b = blockIdx.x, t = threadIdx.x;

  if (b < 512) {
    int n = b;
    const float* yr = y + n * INDIM_;
    double a0 = 0.0, a1 = 0.0;
    for (int d = 0; d < INDIM_; ++d) {
      double yv = (double)yr[d];
      a0 += yv * (double)eW1[d * H_ + t];
      a1 += yv * (double)eW1[d * H_ + t + 256];
    }
    sm.e.hs[t] = tanh(a0 + (double)eb1[t]);
    sm.e.hs[t + 256] = tanh(a1 + (double)eb1[t + 256]);
    __syncthreads();
    int c = t & 63;
    if (t < 128) {
      const float* Wsel = (t < 64) ? Wmu : Wv;
      double acc = 0.0;
      for (int q = 0; q < H_; ++q) acc += sm.e.hs[q] * (double)Wsel[q * D_ + c];
      if (t < 64) {
        double m = acc + (double)bmu[c];
        mu[n * D_ + c] = m;
        sm.e.mu32s[c] = (float)m;
      } else {
        double a = acc + (double)bv[c];
        double var = sp64(a) + 1e-6;
        dvec[n * D_ + c] = -0.5 / var;
        float var32 = sp32cr((float)a) + 1e-6f;
        sm.e.var32s[c] = var32;
        d32[n * D_ + c] = (-0.5f) / var32;
      }
    }
    __syncthreads();
    if (t < 64) {
      float var32 = sm.e.var32s[c];
      float dd = (-0.5f) / var32;
      float eta1 = sm.e.mu32s[c] / var32;
      float neg2d = -2.0f * dd;
      muph[n * D_ + c] = eta1 / neg2d;
    }
  } else if (b < 920) {
    int chunk = (b - 512) * 4 + (t >> 6);
    int l = t & 63;
    if (chunk < 1632) {
      int lr = l & 15, lg = l >> 4;
      const float* src; int C, ct, ks; ushort* dst;
      if (chunk < 64)       { src = dW1;  C = 512; ct = chunk >> 1;  ks = chunk & 1;
                              dst = hF + chunk * 512; }
      else if (chunk < 848) { int c2 = chunk - 64;  src = dWmu; C = 784; ct = c2 / 16; ks = c2 % 16;
                              dst = hF + 32768 + c2 * 512; }
      else                  { int c2 = chunk - 848; src = dWv;  C = 784; ct = c2 / 16; ks = c2 % 16;
                              dst = hF + 434176 + c2 * 512; }
      ushort vals[8];
#pragma unroll
      for (int e = 0; e < 8; ++e)
        vals[e] = bf16rne(src[(ks * 32 + lg * 8 + e) * C + ct * 16 + lr]);
      *(short8v*)(dst + l * 8) = *(short8v*)vals;
    }
  } else if (b < 930) {
    int k = b - 920, i = t;
    const float* Lr = Lraw + k * D_ * D_;
    if (t < 64) {
      for (int j = 0; j < i; ++j) sm.g.Lk[i][j] = Lr[i * D_ + j];
      sm.g.dg[i] = sp64((double)Lr[i * D_ + i]);
    }
    __syncthreads();
#define LKD(r, c) ((c) < (r) ? (double)sm.g.Lk[r][c] : sm.g.dg[r])
    if (t < 64) {
      int j = i;
      sm.g.Li[j][j] = 1.0 / sm.g.dg[j];
      for (int r = j + 1; r < D_; ++r) {
        double s = 0.0;
        for (int m = j; m < r; ++m) s += LKD(r, m) * sm.g.Li[m][j];
        sm.g.Li[r][j] = -s / sm.g.dg[r];
      }
    }
    __syncthreads();
    if (t < 64) {
      for (int j = 0; j < D_; ++j) {
        int m0 = max(i, j);
        double s = 0.0;
        for (int m = m0; m < D_; ++m) s += sm.g.Li[m][i] * sm.g.Li[m][j];
        iJout[k * D_ * D_ + i * D_ + j] = -2.0 * s;
      }
      double rv = (double)muk[k * D_ + i];
      for (int j = 0; j < D_; ++j) {
        double xj = __shfl(rv, j, 64) / sm.g.dg[j];
        if (i == j) rv = xj;
        else if (i > j) rv -= (double)sm.g.Lk[i][j] * xj;
      }
      for (int j = D_ - 1; j >= 0; --j) {
        double xj = __shfl(rv, j, 64) / sm.g.dg[j];
        if (i == j) rv = xj;
        else if (i < j) rv -= (double)sm.g.Lk[j][i] * xj;
      }
      gko[k * D_ + i] = 2.0 * rv;
    }
#undef LKD
    if (k == 0 && t == 0) {
      double m = (double)piraw[0];
      for (int q = 1; q < K_; ++q) m = fmax(m, (double)piraw[q]);
      double ss = 0.0;
      for (int q = 0; q < K_; ++q) ss += exp((double)piraw[q] - m);
      double lse = m + log(ss);
      for (int q = 0; q < K_; ++q) logpi[q] = (double)piraw[q] - lse;
    }
  } else {
    int k = b - 930, i = t;
    const float* Lr = Lraw + k * D_ * D_;
    if (t < 64) {
      for (int j = 0; j < D_; ++j)
        sm.u.Lk[i][j] = (j < i) ? Lr[i * D_ + j] : ((j == i) ? sp32cr(Lr[i * D_ + i]) : 0.0f);
    }
    __syncthreads();
    if (t < 64) {
      for (int j = 0; j < D_; ++j) {
        float s = 0.0f;
        for (int q = 0; q < D_; ++q) s = fmaf(sm.u.Lk[i][q], sm.u.Lk[j][q], s);
        sm.u.A[i][j] = -0.5f * s;
      }
    }
    __syncthreads();
    if (t < 64)
      for (int r = 0; r < D_; ++r)
        J32g[k * 4096 + r * 64 + i] = sm.u.A[r][i];
    int mypiv = i;
    for (int j = 0; j < D_; ++j) {
      __syncthreads();
      if (t < 64) {
        float v = (i >= j) ? fabsf(sm.u.A[i][j]) : -1.0f;
        int ix = i;
        for (int off = 32; off > 0; off >>= 1) {
          float v2 = __shfl_xor(v, off, 64);
          int i2 = __shfl_xor(ix, off, 64);
          if (v2 > v || (v2 == v && i2 < ix)) { v = v2; ix = i2; }
        }
        int p = ix;
        if (i == j) mypiv = p;
        if (p != j) { float tmp = sm.u.A[j][i]; sm.u.A[j][i] = sm.u.A[p][i]; sm.u.A[p][i] = tmp; }
      }
      __syncthreads();
      if (t < 64 && i > j) {
        float rec = 1.0f / sm.u.A[j][j];
        float x = sm.u.A[i][j] * rec;
        sm.u.A[i][j] = x;
        int l = j + 1;
        for (; l + 7 < D_; l += 8) {
          float p0 = sm.u.A[j][l+0], p1 = sm.u.A[j][l+1], p2 = sm.u.A[j][l+2], p3 = sm.u.A[j][l+3];
          float p4 = sm.u.A[j][l+4], p5 = sm.u.A[j][l+5], p6 = sm.u.A[j][l+6], p7 = sm.u.A[j][l+7];
          float o0 = sm.u.A[i][l+0], o1 = sm.u.A[i][l+1], o2 = sm.u.A[i][l+2], o3 = sm.u.A[i][l+3];
          float o4 = sm.u.A[i][l+4], o5 = sm.u.A[i][l+5], o6 = sm.u.A[i][l+6], o7 = sm.u.A[i][l+7];
          o0 = fmaf(x, -p0, o0); o1 = fmaf(x, -p1, o1);
          o2 = fmaf(x, -p2, o2); o3 = fmaf(x, -p3, o3);
          o4 = fmaf(x, -p4, o4); o5 = fmaf(x, -p5, o5);
          o6 = fmaf(x, -p6, o6); o7 = fmaf(x, -p7, o7);
          sm.u.A[i][l+0] = o0; sm.u.A[i][l+1] = o1; sm.u.A[i][l+2] = o2; sm.u.A[i][l+3] = o3;
          sm.u.A[i][l+4] = o4; sm.u.A[i][l+5] = o5; sm.u.A[i][l+6] = o6; sm.u.A[i][l+7] = o7;
        }
        for (; l < D_; ++l) sm.u.A[i][l] = fmaf(x, -sm.u.A[j][l], sm.u.A[i][l]);
      }
    }
    __syncthreads();
    if (t < 64) {
      for (int r = 0; r < D_; ++r)
        LU32g[k * 4096 + r * 64 + i] = sm.u.A[r][i];
      pivg[k * D_ + i] = mypiv;
    }
  }
}

// =============== k_all3: pernk | quad32, 2 waves/block ===============
// blocks: [0,2560) pernk (2 nk each), [2560,5120) quad32 (2 n sharing k)
__global__ __launch_bounds__(128) void k_all3(
    const double* __restrict__ dvec, const double* __restrict__ mu,
    const double* __restrict__ gk, const double* __restrict__ iJg,
    double* __restrict__ parts, float* __restrict__ xs,
    const float* __restrict__ J32g, const float* __restrict__ LU32g,
    const int* __restrict__ pivg, const float* __restrict__ d32g,
    const float* __restrict__ muphg, double* __restrict__ quadg) {
  __shared__ union SM3 {
    struct { float LUs[64][DP1]; int pshare[64]; float dsh[2][64]; float mph[2][64]; } q;
    struct { float Sp[2][2080]; } p;
  } sm;
  int b = blockIdx.x;
  int wv = threadIdx.x >> 6;
  int lane = threadIdx.x & 63;

  if (b < 2560) {
    // ---------------- pernk: f32 left-looking LDS Cholesky (per-wave nk) ----------------
    int nk = b * 2 + wv;
    int n = nk / K_, k = nk - n * K_;
    int i = lane;
    float* Sp = sm.p.Sp[wv];
    int Ti = (i * (i + 1)) >> 1;

    double dnd = dvec[n * 64 + i];
    float dn = (float)dnd;
    double mn = mu[n * 64 + i];
    const double* iJ = iJg + k * 4096;

    float linv = 0.f, ljj = 1.f;
    float pj = (float)iJ[i];
    for (int j = 0; j < 64; ++j) {
      float nx = (j + 1 < 64) ? (float)iJ[(j + 1) * 64 + i] : 0.f;
      float dj = __shfl(dn, j, 64);
      float v = -(dn * pj * dj);
      if (i == j) v -= dn;
      int Tj = (j * (j + 1)) >> 1;
      float a0 = 0.f, a1 = 0.f, a2 = 0.f, a3 = 0.f;
      int q = 0;
      for (; q + 3 < j; q += 4) {
        a0 = fmaf(Sp[Ti + q],     Sp[Tj + q],     a0);
        a1 = fmaf(Sp[Ti + q + 1], Sp[Tj + q + 1], a1);
        a2 = fmaf(Sp[Ti + q + 2], Sp[Tj + q + 2], a2);
        a3 = fmaf(Sp[Ti + q + 3], Sp[Tj + q + 3], a3);
      }
      for (; q < j; ++q) a0 = fmaf(Sp[Ti + q], Sp[Tj + q], a0);
      v -= ((a0 + a1) + (a2 + a3));
      float sj = __shfl(v, j, 64);
      float s_ = sqrtf(fmaxf(sj, 1e-30f));
      float lc = 1.0f / s_;
      float li = (i == j) ? s_ : v * lc;
      if (i >= j) Sp[Ti + j] = li;
      if (i == j) { linv = lc; ljj = s_; }
      pj = nx;
      __syncthreads();
    }

    float rv = (-dn) * (float)gk[k * 64 + i];
    float uv = dn;
    for (int j = 0; j < 64; ++j) {
      float xz = __shfl(rv * linv, j, 64);
      float xu = __shfl(uv * linv, j, 64);
      float lij = (i > j) ? Sp[Ti + j] : 0.f;
      if (i == j) { rv = xz; uv = xu; }
      else { rv = fmaf(-lij, xz, rv); uv = fmaf(-lij, xu, uv); }
    }
    for (int j = 63; j >= 0; --j) {
      float xz = __shfl(rv * linv, j, 64);
      float xu = __shfl(uv * linv, j, 64);
      float lij = (i < j) ? Sp[((j * (j + 1)) >> 1) + i] : 0.f;
      if (i == j) { rv = xz; uv = xu; }
      else { rv = fmaf(-lij, xz, rv); uv = fmaf(-lij, xu, uv); }
    }
    double zsum = (double)rv;
    for (int o = 32; o > 0; o >>= 1) zsum += __shfl_xor(zsum, o, 64);
    double s_nk = -zsum;
    double w1 = s_nk * dnd;
    float tvf = (float)s_nk * uv;
    double dmw = mn * w1;
    for (int o = 32; o > 0; o >>= 1) dmw += __shfl_xor(dmw, o, 64);
    double dwt = w1 * (double)tvf;
    for (int o = 32; o > 0; o >>= 1) dwt += __shfl_xor(dwt, o, 64);
    double sl = log((double)ljj);
    for (int o = 32; o > 0; o >>= 1) sl += __shfl_xor(sl, o, 64);
    if (i == 0) {
      double* pp = parts + nk * 4;
      pp[0] = dmw; pp[1] = dwt; pp[2] = sl;
    }

    float rr[S_];
    {
      uint32_t base = (uint32_t)((nk * 64 + i) * S_);
#pragma unroll
      for (int s = 0; s < S_; ++s)
        rr[s] = jax_normal_f32(0u, 42u, base + s);
    }
    for (int q = 63; q >= 0; --q) {
      float lq = (i < q) ? Sp[((q * (q + 1)) >> 1) + i] : 0.f;
#pragma unroll
      for (int s = 0; s < S_; ++s) {
        float rq = __shfl(rr[s] * linv, q, 64);
        if (i == q) rr[s] = rq;
        else rr[s] = fmaf(-lq, rq, rr[s]);
      }
    }
    float xm = 0.5f * tvf;
#pragma unroll
    for (int s = 0; s < S_; ++s)
      xs[(nk * S_ + s) * 64 + i] = fmaf(0.70710678f, rr[s], xm);
  } else {
    // ---------------- quad32: 2 n's sharing one k (shared LU stage) ----------------
    int b2 = b - 2560;
    int k = b2 % K_;
    int npair = b2 / K_;
    int n = npair * 2 + wv;
    int nk = n * K_ + k;
    int tj = lane;

    for (int r = wv; r < 64; r += 2)
      sm.q.LUs[r][tj] = LU32g[k * 4096 + r * 64 + tj];
    sm.q.dsh[wv][tj] = d32g[n * 64 + tj];
    sm.q.mph[wv][tj] = muphg[n * 64 + tj];
    if (wv == 0) {
      int pv = pivg[k * 64 + tj];
      int perm = tj;
      for (int j = 0; j < 64; ++j) {
        int pj = __shfl(pv, j, 64);
        int vj = __shfl(perm, j, 64);
        int vp = __shfl(perm, pj, 64);
        if (tj == j) perm = vp;
        else if (tj == pj) perm = vj;
      }
      sm.q.pshare[tj] = perm;
    }
    __syncthreads();
    float Tc[64];
#pragma unroll
    for (int i2 = 0; i2 < 64; ++i2) {
      int pr = sm.q.pshare[i2];
      float v = J32g[k * 4096 + pr * 64 + tj];
      if (pr == tj) v = v + sm.q.dsh[wv][tj];
      Tc[i2] = v;
    }
#pragma unroll
    for (int r = 0; r < 64; ++r) {
      float x = Tc[r];
#pragma unroll
      for (int i2 = r + 1; i2 < 64; ++i2)
        Tc[i2] = fmaf(sm.q.LUs[i2][r], -x, Tc[i2]);
    }
#pragma unroll
    for (int r = 63; r >= 0; --r) {
      float x = Tc[r] / sm.q.LUs[r][r];
      Tc[r] = x;
#pragma unroll
      for (int i2 = 0; i2 < r; ++i2)
        Tc[i2] = fmaf(sm.q.LUs[i2][r], -x, Tc[i2]);
    }
    __syncthreads();     // both waves done reading LUs as LU
    // wave 0 phase: write T, symmetrize, reduce, store
    if (wv == 0) {
#pragma unroll
      for (int i2 = 0; i2 < 64; ++i2) sm.q.LUs[i2][tj] = Tc[i2];
    }
    __syncthreads();
    if (wv == 0) {
      double part = 0.0;
#pragma unroll
      for (int d2 = 0; d2 < 64; ++d2) {
        float a = sm.q.dsh[0][d2] * Tc[d2];
        float bq = sm.q.dsh[0][tj] * sm.q.LUs[tj][d2];
        float w = 0.5f * (a + bq);
        float t1 = sm.q.mph[0][d2] * w;
        float t2 = t1 * sm.q.mph[0][tj];
        part += (double)t2;
      }
      for (int off = 32; off > 0; off >>= 1)
        part += __shfl_xor(part, off, 64);
      if (tj == 0) quadg[nk] = part;
    }
    __syncthreads();
    // wave 1 phase
    if (wv == 1) {
#pragma unroll
      for (int i2 = 0; i2 < 64; ++i2) sm.q.LUs[i2][tj] = Tc[i2];
    }
    __syncthreads();
    if (wv == 1) {
      double part = 0.0;
#pragma unroll
      for (int d2 = 0; d2 < 64; ++d2) {
        float a = sm.q.dsh[1][d2] * Tc[d2];
        float bq = sm.q.dsh[1][tj] * sm.q.LUs[tj][d2];
        float w = 0.5f * (a + bq);
        float t1 = sm.q.mph[1][d2] * w;
        float t2 = t1 * sm.q.mph[1][tj];
        part += (double)t2;
      }
      for (int off = 32; off > 0; off >>= 1)
        part += __shfl_xor(part, off, 64);
      if (tj == 0) quadg[nk] = part;
    }
  }
}

// =============== k_all4: dec | softcat ===============
__global__ __launch_bounds__(256) void k_all4(
    const float* __restrict__ xs,
    const ushort* __restrict__ W1F, const ushort* __restrict__ WmuF, const ushort* __restrict__ WvF,
    const float* __restrict__ b1, const float* __restrict__ bmu, const float* __restrict__ bvv,
    float* __restrict__ outm, float* __restrict__ outv,
    const double* __restrict__ parts, const double* __restrict__ quadg,
    const double* __restrict__ logpi,
    float* __restrict__ outz, float* __restrict__ outx) {
  __shared__ __align__(16) union SM4 {
    ushort hdF[32768];
    struct { double lz[K_]; int zc; } s;
  } sm;
  int b = blockIdx.x, t = threadIdx.x;

  if (b < 800) {
    int w = t >> 6, l = t & 63;
    int lr = l & 15, lg = l >> 4;
    int row0 = b * 64;
    int wrow0 = row0 + w * 16;

    short8v xhi[2], xlo[2];
    {
      const float* xrow = xs + (size_t)(wrow0 + lr) * 64 + lg * 8;
#pragma unroll
      for (int ks = 0; ks < 2; ++ks) {
        ushort hi[8], lo[8];
#pragma unroll
        for (int e = 0; e < 8; ++e) {
          float xv = xrow[ks * 32 + e];
          ushort h16 = bf16rne(xv);
          hi[e] = h16;
          lo[e] = bf16rne(xv - bf2f(h16));
        }
        xhi[ks] = *(short8v*)hi;
        xlo[ks] = *(short8v*)lo;
      }
    }

    const short8v* W1v = (const short8v*)W1F;
#pragma unroll 4
    for (int ct = 0; ct < 32; ++ct) {
      f32x4 acc = {0.f, 0.f, 0.f, 0.f};
      short8v b0 = W1v[(ct * 2 + 0) * 64 + l];
      short8v b1v = W1v[(ct * 2 + 1) * 64 + l];
      acc = __builtin_amdgcn_mfma_f32_16x16x32_bf16(xhi[0], b0, acc, 0, 0, 0);
      acc = __builtin_amdgcn_mfma_f32_16x16x32_bf16(xlo[0], b0, acc, 0, 0, 0);
      acc = __builtin_amdgcn_mfma_f32_16x16x32_bf16(xhi[1], b1v, acc, 0, 0, 0);
      acc = __builtin_amdgcn_mfma_f32_16x16x32_bf16(xlo[1], b1v, acc, 0, 0, 0);
      int c = ct * 16 + lr;
      float bb = b1[c];
      int ks = ct >> 1;
      int blk = ((ct & 1) << 1) | (lr >> 3);
      int eo = lr & 7;
#pragma unroll
      for (int r = 0; r < 4; ++r) {
        int l2 = (lg * 4 + r) + 16 * blk;
        sm.hdF[(((w * 16 + ks) * 64) + l2) * 8 + eo] = bf16rne(fast_tanh(acc[r] + bb));
      }
    }
    __syncthreads();

    const short8v* hdv = (const short8v*)sm.hdF;
    const short8v* Wmv = (const short8v*)WmuF;
    const short8v* Wvv = (const short8v*)WvF;
    for (int ci = w; ci < 49; ci += 4) {
      f32x4 aM[4], aV[4];
#pragma unroll
      for (int rg = 0; rg < 4; ++rg) {
        aM[rg] = (f32x4){0.f, 0.f, 0.f, 0.f};
        aV[rg] = (f32x4){0.f, 0.f, 0.f, 0.f};
      }
#pragma unroll 4
      for (int ks = 0; ks < 16; ++ks) {
        short8v bm = Wmv[(ci * 16 + ks) * 64 + l];
        short8v bv = Wvv[(ci * 16 + ks) * 64 + l];
#pragma unroll
        for (int rg = 0; rg < 4; ++rg) {
          short8v ha = hdv[(rg * 16 + ks) * 64 + l];
          aM[rg] = __builtin_amdgcn_mfma_f32_16x16x32_bf16(ha, bm, aM[rg], 0, 0, 0);
          aV[rg] = __builtin_amdgcn_mfma_f32_16x16x32_bf16(ha, bv, aV[rg], 0, 0, 0);
        }
      }
      int c = ci * 16 + lr;
      float bm_ = bmu[c], bv_ = bvv[c];
#pragma unroll
      for (int rg = 0; rg < 4; ++rg) {
        int rbase = (row0 + rg * 16 + lg * 4) * INDIM_ + c;
#pragma unroll
        for (int r = 0; r < 4; ++r) {
          int o = rbase + r * INDIM_;
          outm[o] = aM[rg][r] + bm_;
          outv[o] = fast_sp(aV[rg][r] + bv_) + 1e-6f;
        }
      }
    }
  } else {
    int n = b - 800;
    if (t == 0) {
      double lp[K_];
      double m = -1e300;
      for (int q = 0; q < K_; ++q) {
        const double* pp = parts + (n * K_ + q) * 4;
        double v = pp[0] + quadg[n * K_ + q];
        v = v - 0.25 * pp[1];
        v = v + 32.0 * 0.6931471805599453;
        v = v + pp[2];
        v = v - 32.0 * 1.8378770664093453;
        v = v + logpi[q];
        lp[q] = v;
        m = fmax(m, v);
      }
      double ss = 0.0;
      for (int q = 0; q < K_; ++q) ss += exp(lp[q] - m);
      double lsum = log(ss);
      float best = -INFINITY; int bi = 0;
      for (int q = 0; q < K_; ++q) {
        double l = (lp[q] - m) - lsum;
        sm.s.lz[q] = l;
        float g = jax_gumbel_f32(0u, 7u, (uint32_t)(n * 100 + q));
        float sc = g + (float)l;
        if (sc > best) { best = sc; bi = q; }
      }
      sm.s.zc = bi;
    }
    __syncthreads();
    if (t < K_) outz[n * K_ + t] = (float)sm.s.lz[t];
    if (t < 64) outx[n * D_ + t] = xs[(n * K_ + sm.s.zc) * S_ * D_ + t];
  }
}

// ---------------- launch ----------------
extern "C" void kernel_launch(void* const* d_in, const int* in_sizes, int n_in,
                              void* d_out, int out_size, void* d_ws, size_t ws_size,
                              hipStream_t stream) {
  const float* y     = (const float*)d_in[0];
  const float* eW1   = (const float*)d_in[1];
  const float* eb1   = (const float*)d_in[2];
  const float* eWmu  = (const float*)d_in[3];
  const float* ebmu  = (const float*)d_in[4];
  const float* eWv   = (const float*)d_in[5];
  const float* ebv   = (const float*)d_in[6];
  const float* muk   = (const float*)d_in[7];
  const float* Lraw  = (const float*)d_in[8];
  const float* piraw = (const float*)d_in[9];
  const float* dW1   = (const float*)d_in[10];
  const float* db1   = (const float*)d_in[11];
  const float* dWmu  = (const float*)d_in[12];
  const float* dbmu  = (const float*)d_in[13];
  const float* dWv   = (const float*)d_in[14];
  const float* dbv   = (const float*)d_in[15];

  double* W      = (double*)d_ws;
  double* h      = W;             // region reused as bf16 frag store (hF)
  double* mu     = W + 262144;    // 32768
  double* dvec   = W + 294912;    // 32768
  double* gk     = W + 327680;    // 640
  double* parts  = W + 328704;    // 20480 (5120 x 4)
  double* iJ     = W + 368640;    // 40960
  double* logpi  = W + 409600;    // 16
  double* quadg  = W + 414736;    // 5120
  double* base2  = W + 419856;
  float*  xs     = (float*)base2;                 // 3,276,800 floats
  float*  J32    = xs + 3276800;                  // 40960 floats
  float*  LU32   = J32 + 40960;                   // 40960
  float*  d32    = LU32 + 40960;                  // 32768
  float*  muph   = d32 + 32768;                   // 32768
  int*    piv    = (int*)(muph + 32768);          // 640 ints

  ushort* hF   = (ushort*)h;
  ushort* W1F  = hF;
  ushort* WmuF = hF + 32768;
  ushort* WvF  = hF + 434176;

  float* outm = (float*)d_out;            // (N,K,S,784)
  float* outv = outm + 40140800;          // (N,K,S,784)
  float* outx = outm + 80281600;          // (N,64)
  float* outz = outm + 80314368;          // (N,10)

  k_all1<<<940, 256, 0, stream>>>(y, eW1, eb1, eWmu, ebmu, eWv, ebv,
                                  mu, dvec, d32, muph,
                                  dW1, dWmu, dWv, hF,
                                  Lraw, piraw, muk, iJ, gk, logpi,
                                  J32, LU32, piv);
  k_all3<<<5120, 128, 0, stream>>>(dvec, mu, gk, iJ, parts, xs,
                                   J32, LU32, piv, d32, muph, quadg);
  k_all4<<<1312, 256, 0, stream>>>(xs, W1F, WmuF, WvF, db1, dbmu, dbv,
                                   outm, outv, parts, quadg, logpi, outz, outx);
}

// Round 19
// 667.681 us; speedup vs baseline: 1.0497x; 1.0497x over previous
//
#include <hip/hip_runtime.h>
#include <math.h>
#include <stdint.h>

#define N_ 512
#define D_ 64
#define K_ 10
#define S_ 10
#define INDIM_ 784
#define H_ 512
#define DP1 (D_ + 1)

typedef __attribute__((ext_vector_type(8))) short short8v;
typedef __attribute__((ext_vector_type(4))) float f32x4;

// ---------------- JAX Threefry-2x32 (20 rounds) ----------------
__device__ __forceinline__ uint32_t rotl32(uint32_t v, int r) { return (v << r) | (v >> (32 - r)); }

__device__ __forceinline__ void threefry2x32(uint32_t k0, uint32_t k1,
                                             uint32_t x0, uint32_t x1,
                                             uint32_t& o0, uint32_t& o1) {
  uint32_t k2 = k0 ^ k1 ^ 0x1BD11BDAu;
  x0 += k0; x1 += k1;
#define TFR(r) { x0 += x1; x1 = rotl32(x1, r); x1 ^= x0; }
  TFR(13) TFR(15) TFR(26) TFR(6)
  x0 += k1; x1 += k2 + 1u;
  TFR(17) TFR(29) TFR(16) TFR(24)
  x0 += k2; x1 += k0 + 2u;
  TFR(13) TFR(15) TFR(26) TFR(6)
  x0 += k0; x1 += k1 + 3u;
  TFR(17) TFR(29) TFR(16) TFR(24)
  x0 += k1; x1 += k2 + 4u;
  TFR(13) TFR(15) TFR(26) TFR(6)
  x0 += k2; x1 += k0 + 5u;
#undef TFR
  o0 = x0; o1 = x1;
}

__device__ __forceinline__ uint32_t jax_bits32(uint32_t k0, uint32_t k1, uint32_t idx) {
  uint32_t o0, o1; threefry2x32(k0, k1, 0u, idx, o0, o1);
  return o0 ^ o1;
}

__device__ __forceinline__ float bits_to_u01(uint32_t bits) {
  return __uint_as_float((bits >> 9) | 0x3F800000u) - 1.0f;
}

__device__ __forceinline__ float erfinv_f32(float x) {
  float w = -log1pf(-x * x);
  float p;
  if (w < 5.0f) {
    w = w - 2.5f;
    p = 2.81022636e-08f;
    p = fmaf(p, w, 3.43273939e-07f);
    p = fmaf(p, w, -3.5233877e-06f);
    p = fmaf(p, w, -4.39150654e-06f);
    p = fmaf(p, w, 0.00021858087f);
    p = fmaf(p, w, -0.00125372503f);
    p = fmaf(p, w, -0.00417768164f);
    p = fmaf(p, w, 0.246640727f);
    p = fmaf(p, w, 1.50140941f);
  } else {
    w = sqrtf(w) - 3.0f;
    p = -0.000200214257f;
    p = fmaf(p, w, 0.000100950558f);
    p = fmaf(p, w, 0.00134934322f);
    p = fmaf(p, w, -0.00367342844f);
    p = fmaf(p, w, 0.00573950773f);
    p = fmaf(p, w, -0.0076224613f);
    p = fmaf(p, w, 0.00943887047f);
    p = fmaf(p, w, 1.00167406f);
    p = fmaf(p, w, 2.83297682f);
  }
  return p * x;
}

__device__ __forceinline__ float jax_normal_f32(uint32_t k0, uint32_t k1, uint32_t idx) {
  uint32_t bits = jax_bits32(k0, k1, idx);
  float u = bits_to_u01(bits);
  const float lo = -0.99999994f;
  float v = u * (1.0f - lo) + lo;
  v = fmaxf(lo, v);
  return 1.41421356f * erfinv_f32(v);
}

__device__ __forceinline__ float jax_gumbel_f32(uint32_t k0, uint32_t k1, uint32_t idx) {
  uint32_t bits = jax_bits32(k0, k1, idx);
  float u = bits_to_u01(bits);
  const float tiny = 1.17549435e-38f;
  float v = u * (1.0f - tiny) + tiny;
  v = fmaxf(tiny, v);
  return -logf(-logf(v));
}

__device__ __forceinline__ float sp32(float x) { return fmaxf(x, 0.f) + log1pf(expf(-fabsf(x))); }
__device__ __forceinline__ float sp32cr(float x) {
  double xd = (double)x;
  return (float)(fmax(xd, 0.0) + log1p(exp(-fabs(xd))));
}
__device__ __forceinline__ double sp64(double x) { return fmax(x, 0.0) + log1p(exp(-fabs(x))); }

__device__ __forceinline__ float fast_sp(float x) {
  float e = __expf(-fabsf(x));
  return fmaxf(x, 0.f) + __logf(1.0f + e);
}
__device__ __forceinline__ float fast_tanh(float x) {
  float xc = fminf(fmaxf(2.0f * x, -30.0f), 30.0f);
  float e = __expf(xc);
  float r = __builtin_amdgcn_rcpf(e + 1.0f);
  return fmaf(-2.0f, r, 1.0f);
}

__device__ __forceinline__ ushort bf16rne(float f) {
  uint32_t u = __float_as_uint(f);
  uint32_t r = (u + 0x7FFFu + ((u >> 16) & 1u)) >> 16;
  return (ushort)r;
}
__device__ __forceinline__ float bf2f(ushort b) { return __uint_as_float(((uint32_t)b) << 16); }

// uniform-lane broadcasts via v_readlane (SGPR path, off the DS pipe)
__device__ __forceinline__ float rdlane_f(float v, int l) {
  return __int_as_float(__builtin_amdgcn_readlane(__float_as_int(v), l));
}
__device__ __forceinline__ double rdlane_d(double v, int l) {
  union { double d; int u[2]; } x; x.d = v;
  int lo = __builtin_amdgcn_readlane(x.u[0], l);
  int hi = __builtin_amdgcn_readlane(x.u[1], l);
  union { double d; int u[2]; } y2; y2.u[0] = lo; y2.u[1] = hi;
  return y2.d;
}

// =============== k_all1: encoder(+muvar) | prep | gmm | lu32 ===============
__global__ __launch_bounds__(256) void k_all1(
    const float* __restrict__ y, const float* __restrict__ eW1, const float* __restrict__ eb1,
    const float* __restrict__ Wmu, const float* __restrict__ bmu,
    const float* __restrict__ Wv, const float* __restrict__ bv,
    double* __restrict__ mu, double* __restrict__ dvec,
    float* __restrict__ d32, float* __restrict__ muph,
    const float* __restrict__ dW1, const float* __restrict__ dWmu, const float* __restrict__ dWv,
    ushort* __restrict__ hF,
    const float* __restrict__ Lraw, const float* __restrict__ piraw, const float* __restrict__ muk,
    double* __restrict__ iJout, double* __restrict__ gko, double* __restrict__ logpi,
    float* __restrict__ J32g, float* __restrict__ LU32g, int* __restrict__ pivg) {
  __shared__ union SM1 {
    struct { double hs[512]; float mu32s[64]; float var32s[64]; } e;
    struct { float Lk[64][DP1]; double dg[64]; double Li[64][DP1]; } g;
    struct { float Lk[64][DP1]; float A[64][DP1]; } u;
  } sm;
  int b = blockIdx.x, t = threadIdx.x;

  if (b < 512) {
    int n = b;
    const float* yr = y + n * INDIM_;
    double a0 = 0.0, a1 = 0.0;
    for (int d = 0; d < INDIM_; ++d) {
      double yv = (double)yr[d];
      a0 += yv * (double)eW1[d * H_ + t];
      a1 += yv * (double)eW1[d * H_ + t + 256];
    }
    sm.e.hs[t] = tanh(a0 + (double)eb1[t]);
    sm.e.hs[t + 256] = tanh(a1 + (double)eb1[t + 256]);
    __syncthreads();
    int c = t & 63;
    if (t < 128) {
      const float* Wsel = (t < 64) ? Wmu : Wv;
      double acc = 0.0;
      for (int q = 0; q < H_; ++q) acc += sm.e.hs[q] * (double)Wsel[q * D_ + c];
      if (t < 64) {
        double m = acc + (double)bmu[c];
        mu[n * D_ + c] = m;
        sm.e.mu32s[c] = (float)m;
      } else {
        double a = acc + (double)bv[c];
        double var = sp64(a) + 1e-6;
        dvec[n * D_ + c] = -0.5 / var;
        float var32 = sp32cr((float)a) + 1e-6f;
        sm.e.var32s[c] = var32;
        d32[n * D_ + c] = (-0.5f) / var32;
      }
    }
    __syncthreads();
    if (t < 64) {
      float var32 = sm.e.var32s[c];
      float dd = (-0.5f) / var32;
      float eta1 = sm.e.mu32s[c] / var32;
      float neg2d = -2.0f * dd;
      muph[n * D_ + c] = eta1 / neg2d;
    }
  } else if (b < 920) {
    int chunk = (b - 512) * 4 + (t >> 6);
    int l = t & 63;
    if (chunk < 1632) {
      int lr = l & 15, lg = l >> 4;
      const float* src; int C, ct, ks; ushort* dst;
      if (chunk < 64)       { src = dW1;  C = 512; ct = chunk >> 1;  ks = chunk & 1;
                              dst = hF + chunk * 512; }
      else if (chunk < 848) { int c2 = chunk - 64;  src = dWmu; C = 784; ct = c2 / 16; ks = c2 % 16;
                              dst = hF + 32768 + c2 * 512; }
      else                  { int c2 = chunk - 848; src = dWv;  C = 784; ct = c2 / 16; ks = c2 % 16;
                              dst = hF + 434176 + c2 * 512; }
      ushort vals[8];
#pragma unroll
      for (int e = 0; e < 8; ++e)
        vals[e] = bf16rne(src[(ks * 32 + lg * 8 + e) * C + ct * 16 + lr]);
      *(short8v*)(dst + l * 8) = *(short8v*)vals;
    }
  } else if (b < 930) {
    int k = b - 920, i = t;
    const float* Lr = Lraw + k * D_ * D_;
    if (t < 64) {
      for (int j = 0; j < i; ++j) sm.g.Lk[i][j] = Lr[i * D_ + j];
      sm.g.dg[i] = sp64((double)Lr[i * D_ + i]);
    }
    __syncthreads();
#define LKD(r, c) ((c) < (r) ? (double)sm.g.Lk[r][c] : sm.g.dg[r])
    if (t < 64) {
      int j = i;
      sm.g.Li[j][j] = 1.0 / sm.g.dg[j];
      for (int r = j + 1; r < D_; ++r) {
        double s = 0.0;
        for (int m = j; m < r; ++m) s += LKD(r, m) * sm.g.Li[m][j];
        sm.g.Li[r][j] = -s / sm.g.dg[r];
      }
    }
    __syncthreads();
    if (t < 64) {
      for (int j = 0; j < D_; ++j) {
        int m0 = max(i, j);
        double s = 0.0;
        for (int m = m0; m < D_; ++m) s += sm.g.Li[m][i] * sm.g.Li[m][j];
        iJout[k * D_ * D_ + i * D_ + j] = -2.0 * s;
      }
      double rv = (double)muk[k * D_ + i];
      for (int j = 0; j < D_; ++j) {
        double xj = rdlane_d(rv, j) / sm.g.dg[j];
        if (i == j) rv = xj;
        else if (i > j) rv -= (double)sm.g.Lk[i][j] * xj;
      }
      for (int j = D_ - 1; j >= 0; --j) {
        double xj = rdlane_d(rv, j) / sm.g.dg[j];
        if (i == j) rv = xj;
        else if (i < j) rv -= (double)sm.g.Lk[j][i] * xj;
      }
      gko[k * D_ + i] = 2.0 * rv;
    }
#undef LKD
    if (k == 0 && t == 0) {
      double m = (double)piraw[0];
      for (int q = 1; q < K_; ++q) m = fmax(m, (double)piraw[q]);
      double ss = 0.0;
      for (int q = 0; q < K_; ++q) ss += exp((double)piraw[q] - m);
      double lse = m + log(ss);
      for (int q = 0; q < K_; ++q) logpi[q] = (double)piraw[q] - lse;
    }
  } else {
    int k = b - 930, i = t;
    const float* Lr = Lraw + k * D_ * D_;
    if (t < 64) {
      for (int j = 0; j < D_; ++j)
        sm.u.Lk[i][j] = (j < i) ? Lr[i * D_ + j] : ((j == i) ? sp32cr(Lr[i * D_ + i]) : 0.0f);
    }
    __syncthreads();
    if (t < 64) {
      for (int j = 0; j < D_; ++j) {
        float s = 0.0f;
        for (int q = 0; q < D_; ++q) s = fmaf(sm.u.Lk[i][q], sm.u.Lk[j][q], s);
        sm.u.A[i][j] = -0.5f * s;
      }
    }
    __syncthreads();
    if (t < 64)
      for (int r = 0; r < D_; ++r)
        J32g[k * 4096 + r * 64 + i] = sm.u.A[r][i];
    int mypiv = i;
    for (int j = 0; j < D_; ++j) {
      __syncthreads();
      if (t < 64) {
        float v = (i >= j) ? fabsf(sm.u.A[i][j]) : -1.0f;
        int ix = i;
        for (int off = 32; off > 0; off >>= 1) {
          float v2 = __shfl_xor(v, off, 64);
          int i2 = __shfl_xor(ix, off, 64);
          if (v2 > v || (v2 == v && i2 < ix)) { v = v2; ix = i2; }
        }
        int p = ix;
        if (i == j) mypiv = p;
        if (p != j) { float tmp = sm.u.A[j][i]; sm.u.A[j][i] = sm.u.A[p][i]; sm.u.A[p][i] = tmp; }
      }
      __syncthreads();
      if (t < 64 && i > j) {
        float rec = 1.0f / sm.u.A[j][j];
        float x = sm.u.A[i][j] * rec;
        sm.u.A[i][j] = x;
        int l = j + 1;
        for (; l + 7 < D_; l += 8) {
          float p0 = sm.u.A[j][l+0], p1 = sm.u.A[j][l+1], p2 = sm.u.A[j][l+2], p3 = sm.u.A[j][l+3];
          float p4 = sm.u.A[j][l+4], p5 = sm.u.A[j][l+5], p6 = sm.u.A[j][l+6], p7 = sm.u.A[j][l+7];
          float o0 = sm.u.A[i][l+0], o1 = sm.u.A[i][l+1], o2 = sm.u.A[i][l+2], o3 = sm.u.A[i][l+3];
          float o4 = sm.u.A[i][l+4], o5 = sm.u.A[i][l+5], o6 = sm.u.A[i][l+6], o7 = sm.u.A[i][l+7];
          o0 = fmaf(x, -p0, o0); o1 = fmaf(x, -p1, o1);
          o2 = fmaf(x, -p2, o2); o3 = fmaf(x, -p3, o3);
          o4 = fmaf(x, -p4, o4); o5 = fmaf(x, -p5, o5);
          o6 = fmaf(x, -p6, o6); o7 = fmaf(x, -p7, o7);
          sm.u.A[i][l+0] = o0; sm.u.A[i][l+1] = o1; sm.u.A[i][l+2] = o2; sm.u.A[i][l+3] = o3;
          sm.u.A[i][l+4] = o4; sm.u.A[i][l+5] = o5; sm.u.A[i][l+6] = o6; sm.u.A[i][l+7] = o7;
        }
        for (; l < D_; ++l) sm.u.A[i][l] = fmaf(x, -sm.u.A[j][l], sm.u.A[i][l]);
      }
    }
    __syncthreads();
    if (t < 64) {
      for (int r = 0; r < D_; ++r)
        LU32g[k * 4096 + r * 64 + i] = sm.u.A[r][i];
      pivg[k * D_ + i] = mypiv;
    }
  }
}

// =============== k_all3: pernk | quad32 (64 threads, R17 shape + readlane) ===============
// blocks: [0,5120) pernk, [5120,10240) quad32
__global__ __launch_bounds__(64) void k_all3(
    const double* __restrict__ dvec, const double* __restrict__ mu,
    const double* __restrict__ gk, const double* __restrict__ iJg,
    double* __restrict__ parts, float* __restrict__ xs,
    const float* __restrict__ J32g, const float* __restrict__ LU32g,
    const int* __restrict__ pivg, const float* __restrict__ d32g,
    const float* __restrict__ muphg, double* __restrict__ quadg) {
  __shared__ union SM3 {
    struct { float LUs[64][DP1]; float dsh[64]; float mph[64]; int pshare[64]; } q;
    struct { float Sp[2080]; } p;
  } sm;
  int b = blockIdx.x;

  if (b < 5120) {
    // ---------------- pernk: f32 left-looking LDS Cholesky ----------------
    int nk = b;
    int n = nk / K_, k = nk - n * K_;
    int i = threadIdx.x;
    float* Sp = sm.p.Sp;
    int Ti = (i * (i + 1)) >> 1;

    double dnd = dvec[n * 64 + i];
    float dn = (float)dnd;
    double mn = mu[n * 64 + i];
    const double* iJ = iJg + k * 4096;

    float linv = 0.f, ljj = 1.f;
    float pj = (float)iJ[i];
    for (int j = 0; j < 64; ++j) {
      float nx = (j + 1 < 64) ? (float)iJ[(j + 1) * 64 + i] : 0.f;
      float dj = rdlane_f(dn, j);
      float v = -(dn * pj * dj);
      if (i == j) v -= dn;
      int Tj = (j * (j + 1)) >> 1;
      float a0 = 0.f, a1 = 0.f, a2 = 0.f, a3 = 0.f;
      int q = 0;
      for (; q + 3 < j; q += 4) {
        a0 = fmaf(Sp[Ti + q],     Sp[Tj + q],     a0);
        a1 = fmaf(Sp[Ti + q + 1], Sp[Tj + q + 1], a1);
        a2 = fmaf(Sp[Ti + q + 2], Sp[Tj + q + 2], a2);
        a3 = fmaf(Sp[Ti + q + 3], Sp[Tj + q + 3], a3);
      }
      for (; q < j; ++q) a0 = fmaf(Sp[Ti + q], Sp[Tj + q], a0);
      v -= ((a0 + a1) + (a2 + a3));
      float sj = rdlane_f(v, j);
      float s_ = sqrtf(fmaxf(sj, 1e-30f));
      float lc = 1.0f / s_;
      float li = (i == j) ? s_ : v * lc;
      if (i >= j) Sp[Ti + j] = li;
      if (i == j) { linv = lc; ljj = s_; }
      pj = nx;
      __syncthreads();
    }

    float rv = (-dn) * (float)gk[k * 64 + i];
    float uv = dn;
    for (int j = 0; j < 64; ++j) {
      float xz = rdlane_f(rv * linv, j);
      float xu = rdlane_f(uv * linv, j);
      float lij = (i > j) ? Sp[Ti + j] : 0.f;
      if (i == j) { rv = xz; uv = xu; }
      else { rv = fmaf(-lij, xz, rv); uv = fmaf(-lij, xu, uv); }
    }
    for (int j = 63; j >= 0; --j) {
      float xz = rdlane_f(rv * linv, j);
      float xu = rdlane_f(uv * linv, j);
      float lij = (i < j) ? Sp[((j * (j + 1)) >> 1) + i] : 0.f;
      if (i == j) { rv = xz; uv = xu; }
      else { rv = fmaf(-lij, xz, rv); uv = fmaf(-lij, xu, uv); }
    }
    double zsum = (double)rv;
    for (int o = 32; o > 0; o >>= 1) zsum += __shfl_xor(zsum, o, 64);
    double s_nk = -zsum;
    double w1 = s_nk * dnd;
    float tvf = (float)s_nk * uv;
    double dmw = mn * w1;
    for (int o = 32; o > 0; o >>= 1) dmw += __shfl_xor(dmw, o, 64);
    double dwt = w1 * (double)tvf;
    for (int o = 32; o > 0; o >>= 1) dwt += __shfl_xor(dwt, o, 64);
    double sl = log((double)ljj);
    for (int o = 32; o > 0; o >>= 1) sl += __shfl_xor(sl, o, 64);
    if (i == 0) {
      double* pp = parts + nk * 4;
      pp[0] = dmw; pp[1] = dwt; pp[2] = sl;
    }

    float rr[S_];
    {
      uint32_t base = (uint32_t)((nk * 64 + i) * S_);
#pragma unroll
      for (int s = 0; s < S_; ++s)
        rr[s] = jax_normal_f32(0u, 42u, base + s);
    }
    for (int q = 63; q >= 0; --q) {
      float lq = (i < q) ? Sp[((q * (q + 1)) >> 1) + i] : 0.f;
#pragma unroll
      for (int s = 0; s < S_; ++s) {
        float rq = rdlane_f(rr[s] * linv, q);
        if (i == q) rr[s] = rq;
        else rr[s] = fmaf(-lq, rq, rr[s]);
      }
    }
    float xm = 0.5f * tvf;
#pragma unroll
    for (int s = 0; s < S_; ++s)
      xs[(nk * S_ + s) * 64 + i] = fmaf(0.70710678f, rr[s], xm);
  } else {
    // ---------------- quad32 (bit-identical DAG; readlane perm build) ----------------
    int nk = b - 5120;
    int n = nk / K_, k = nk - n * K_;
    int tj = threadIdx.x;
    for (int r = 0; r < D_; ++r) sm.q.LUs[r][tj] = LU32g[k * 4096 + r * 64 + tj];
    sm.q.dsh[tj] = d32g[n * 64 + tj];
    sm.q.mph[tj] = muphg[n * 64 + tj];
    int pv = pivg[k * 64 + tj];
    int perm = tj;
    for (int j = 0; j < 64; ++j) {
      int pj = __builtin_amdgcn_readlane(pv, j);
      int vj = __builtin_amdgcn_readlane(perm, j);
      int vp = __builtin_amdgcn_readlane(perm, pj);
      if (tj == j) perm = vp;
      else if (tj == pj) perm = vj;
    }
    sm.q.pshare[tj] = perm;
    __syncthreads();
    float Tc[64];
#pragma unroll
    for (int i2 = 0; i2 < 64; ++i2) {
      int pr = sm.q.pshare[i2];
      float v = J32g[k * 4096 + pr * 64 + tj];
      if (pr == tj) v = v + sm.q.dsh[tj];
      Tc[i2] = v;
    }
#pragma unroll
    for (int r = 0; r < 64; ++r) {
      float x = Tc[r];
#pragma unroll
      for (int i2 = r + 1; i2 < 64; ++i2)
        Tc[i2] = fmaf(sm.q.LUs[i2][r], -x, Tc[i2]);
    }
#pragma unroll
    for (int r = 63; r >= 0; --r) {
      float x = Tc[r] / sm.q.LUs[r][r];
      Tc[r] = x;
#pragma unroll
      for (int i2 = 0; i2 < r; ++i2)
        Tc[i2] = fmaf(sm.q.LUs[i2][r], -x, Tc[i2]);
    }
    __syncthreads();
#pragma unroll
    for (int i2 = 0; i2 < 64; ++i2) sm.q.LUs[i2][tj] = Tc[i2];
    __syncthreads();
    double part = 0.0;
#pragma unroll
    for (int d2 = 0; d2 < 64; ++d2) {
      float a = sm.q.dsh[d2] * Tc[d2];
      float bq = sm.q.dsh[tj] * sm.q.LUs[tj][d2];
      float w = 0.5f * (a + bq);
      float t1 = sm.q.mph[d2] * w;
      float t2 = t1 * sm.q.mph[tj];
      part += (double)t2;
    }
    for (int off = 32; off > 0; off >>= 1)
      part += __shfl_xor(part, off, 64);
    if (tj == 0) quadg[nk] = part;
  }
}

// =============== k_all4: dec | softcat ===============
__global__ __launch_bounds__(256) void k_all4(
    const float* __restrict__ xs,
    const ushort* __restrict__ W1F, const ushort* __restrict__ WmuF, const ushort* __restrict__ WvF,
    const float* __restrict__ b1, const float* __restrict__ bmu, const float* __restrict__ bvv,
    float* __restrict__ outm, float* __restrict__ outv,
    const double* __restrict__ parts, const double* __restrict__ quadg,
    const double* __restrict__ logpi,
    float* __restrict__ outz, float* __restrict__ outx) {
  __shared__ __align__(16) union SM4 {
    ushort hdF[32768];
    struct { double lz[K_]; int zc; } s;
  } sm;
  int b = blockIdx.x, t = threadIdx.x;

  if (b < 800) {
    int w = t >> 6, l = t & 63;
    int lr = l & 15, lg = l >> 4;
    int row0 = b * 64;
    int wrow0 = row0 + w * 16;

    short8v xhi[2], xlo[2];
    {
      const float* xrow = xs + (size_t)(wrow0 + lr) * 64 + lg * 8;
#pragma unroll
      for (int ks = 0; ks < 2; ++ks) {
        ushort hi[8], lo[8];
#pragma unroll
        for (int e = 0; e < 8; ++e) {
          float xv = xrow[ks * 32 + e];
          ushort h16 = bf16rne(xv);
          hi[e] = h16;
          lo[e] = bf16rne(xv - bf2f(h16));
        }
        xhi[ks] = *(short8v*)hi;
        xlo[ks] = *(short8v*)lo;
      }
    }

    const short8v* W1v = (const short8v*)W1F;
#pragma unroll 4
    for (int ct = 0; ct < 32; ++ct) {
      f32x4 acc = {0.f, 0.f, 0.f, 0.f};
      short8v b0 = W1v[(ct * 2 + 0) * 64 + l];
      short8v b1v = W1v[(ct * 2 + 1) * 64 + l];
      acc = __builtin_amdgcn_mfma_f32_16x16x32_bf16(xhi[0], b0, acc, 0, 0, 0);
      acc = __builtin_amdgcn_mfma_f32_16x16x32_bf16(xlo[0], b0, acc, 0, 0, 0);
      acc = __builtin_amdgcn_mfma_f32_16x16x32_bf16(xhi[1], b1v, acc, 0, 0, 0);
      acc = __builtin_amdgcn_mfma_f32_16x16x32_bf16(xlo[1], b1v, acc, 0, 0, 0);
      int c = ct * 16 + lr;
      float bb = b1[c];
      int ks = ct >> 1;
      int blk = ((ct & 1) << 1) | (lr >> 3);
      int eo = lr & 7;
#pragma unroll
      for (int r = 0; r < 4; ++r) {
        int l2 = (lg * 4 + r) + 16 * blk;
        sm.hdF[(((w * 16 + ks) * 64) + l2) * 8 + eo] = bf16rne(fast_tanh(acc[r] + bb));
      }
    }
    __syncthreads();

    const short8v* hdv = (const short8v*)sm.hdF;
    const short8v* Wmv = (const short8v*)WmuF;
    const short8v* Wvv = (const short8v*)WvF;
    for (int ci = w; ci < 49; ci += 4) {
      f32x4 aM[4], aV[4];
#pragma unroll
      for (int rg = 0; rg < 4; ++rg) {
        aM[rg] = (f32x4){0.f, 0.f, 0.f, 0.f};
        aV[rg] = (f32x4){0.f, 0.f, 0.f, 0.f};
      }
#pragma unroll 4
      for (int ks = 0; ks < 16; ++ks) {
        short8v bm = Wmv[(ci * 16 + ks) * 64 + l];
        short8v bv = Wvv[(ci * 16 + ks) * 64 + l];
#pragma unroll
        for (int rg = 0; rg < 4; ++rg) {
          short8v ha = hdv[(rg * 16 + ks) * 64 + l];
          aM[rg] = __builtin_amdgcn_mfma_f32_16x16x32_bf16(ha, bm, aM[rg], 0, 0, 0);
          aV[rg] = __builtin_amdgcn_mfma_f32_16x16x32_bf16(ha, bv, aV[rg], 0, 0, 0);
        }
      }
      int c = ci * 16 + lr;
      float bm_ = bmu[c], bv_ = bvv[c];
#pragma unroll
      for (int rg = 0; rg < 4; ++rg) {
        int rbase = (row0 + rg * 16 + lg * 4) * INDIM_ + c;
#pragma unroll
        for (int r = 0; r < 4; ++r) {
          int o = rbase + r * INDIM_;
          outm[o] = aM[rg][r] + bm_;
          outv[o] = fast_sp(aV[rg][r] + bv_) + 1e-6f;
        }
      }
    }
  } else {
    int n = b - 800;
    if (t == 0) {
      double lp[K_];
      double m = -1e300;
      for (int q = 0; q < K_; ++q) {
        const double* pp = parts + (n * K_ + q) * 4;
        double v = pp[0] + quadg[n * K_ + q];
        v = v - 0.25 * pp[1];
        v = v + 32.0 * 0.6931471805599453;
        v = v + pp[2];
        v = v - 32.0 * 1.8378770664093453;
        v = v + logpi[q];
        lp[q] = v;
        m = fmax(m, v);
      }
      double ss = 0.0;
      for (int q = 0; q < K_; ++q) ss += exp(lp[q] - m);
      double lsum = log(ss);
      float best = -INFINITY; int bi = 0;
      for (int q = 0; q < K_; ++q) {
        double l = (lp[q] - m) - lsum;
        sm.s.lz[q] = l;
        float g = jax_gumbel_f32(0u, 7u, (uint32_t)(n * 100 + q));
        float sc = g + (float)l;
        if (sc > best) { best = sc; bi = q; }
      }
      sm.s.zc = bi;
    }
    __syncthreads();
    if (t < K_) outz[n * K_ + t] = (float)sm.s.lz[t];
    if (t < 64) outx[n * D_ + t] = xs[(n * K_ + sm.s.zc) * S_ * D_ + t];
  }
}

// ---------------- launch ----------------
extern "C" void kernel_launch(void* const* d_in, const int* in_sizes, int n_in,
                              void* d_out, int out_size, void* d_ws, size_t ws_size,
                              hipStream_t stream) {
  const float* y     = (const float*)d_in[0];
  const float* eW1   = (const float*)d_in[1];
  const float* eb1   = (const float*)d_in[2];
  const float* eWmu  = (const float*)d_in[3];
  const float* ebmu  = (const float*)d_in[4];
  const float* eWv   = (const float*)d_in[5];
  const float* ebv   = (const float*)d_in[6];
  const float* muk   = (const float*)d_in[7];
  const float* Lraw  = (const float*)d_in[8];
  const float* piraw = (const float*)d_in[9];
  const float* dW1   = (const float*)d_in[10];
  const float* db1   = (const float*)d_in[11];
  const float* dWmu  = (const float*)d_in[12];
  const float* dbmu  = (const float*)d_in[13];
  const float* dWv   = (const float*)d_in[14];
  const float* dbv   = (const float*)d_in[15];

  double* W      = (double*)d_ws;
  double* h      = W;             // region reused as bf16 frag store (hF)
  double* mu     = W + 262144;    // 32768
  double* dvec   = W + 294912;    // 32768
  double* gk     = W + 327680;    // 640
  double* parts  = W + 328704;    // 20480 (5120 x 4)
  double* iJ     = W + 368640;    // 40960
  double* logpi  = W + 409600;    // 16
  double* quadg  = W + 414736;    // 5120
  double* base2  = W + 419856;
  float*  xs     = (float*)base2;                 // 3,276,800 floats
  float*  J32    = xs + 3276800;                  // 40960 floats
  float*  LU32   = J32 + 40960;                   // 40960
  float*  d32    = LU32 + 40960;                  // 32768
  float*  muph   = d32 + 32768;                   // 32768
  int*    piv    = (int*)(muph + 32768);          // 640 ints

  ushort* hF   = (ushort*)h;
  ushort* W1F  = hF;
  ushort* WmuF = hF + 32768;
  ushort* WvF  = hF + 434176;

  float* outm = (float*)d_out;            // (N,K,S,784)
  float* outv = outm + 40140800;          // (N,K,S,784)
  float* outx = outm + 80281600;          // (N,64)
  float* outz = outm + 80314368;          // (N,10)

  k_all1<<<940, 256, 0, stream>>>(y, eW1, eb1, eWmu, ebmu, eWv, ebv,
                                  mu, dvec, d32, muph,
                                  dW1, dWmu, dWv, hF,
                                  Lraw, piraw, muk, iJ, gk, logpi,
                                  J32, LU32, piv);
  k_all3<<<10240, 64, 0, stream>>>(dvec, mu, gk, iJ, parts, xs,
                                   J32, LU32, piv, d32, muph, quadg);
  k_all4<<<1312, 256, 0, stream>>>(xs, W1F, WmuF, WvF, db1, dbmu, dbv,
                                   outm, outv, parts, quadg, logpi, outz, outx);
}